// Round 11
// baseline (178.081 us; speedup 1.0000x reference)
//
#include <hip/hip_runtime.h>
#include <math.h>

#define TWO_H 4096
#define HALF_H 2048
#define NGROUPS 8
#define BLOCK 256
#define WPB 4      // waves per block
#define GRID 2048  // 8192 waves; pairs of rows per wave, grid-stride over pairs

typedef int    vi4 __attribute__((ext_vector_type(4)));
typedef float  vf4 __attribute__((ext_vector_type(4)));
typedef __fp16 vh2 __attribute__((ext_vector_type(2)));

// One WAVE per PAIR of consecutive rows. The pair shares one wscale/bias
// chunk load (same expert group; per-row fallback if the pair straddles a
// boundary). Halves cached-operand VMEM traffic and gives cross-row MLP
// over the shuffle-reduce join. No LDS, no barriers.
__global__ __launch_bounds__(BLOCK, 4) void swiglu_requant_kernel(
    const int* __restrict__ x,         // [N, 4096] int32
    const float* __restrict__ wscale,  // [G, 4096]
    const float* __restrict__ ascale,  // [N]
    const float* __restrict__ bias,    // [4096]
    const float* __restrict__ qscale,  // [G]
    const int* __restrict__ gindex,    // [G]
    int* __restrict__ out,             // [N, 2048] int32 (int8 values widened)
    int n_rows)
{
    const int lane   = threadIdx.x & 63;
    const int wid    = blockIdx.x * WPB + (threadIdx.x >> 6);
    const int nwaves = GRID * WPB;

    int cum[NGROUPS];
    {
        int c = 0;
#pragma unroll
        for (int g = 0; g < NGROUPS; ++g) { c += gindex[g]; cum[g] = c; }
    }
#define GID_OF(row, dst) { int _g = 0; _Pragma("unroll") \
    for (int g = 0; g < NGROUPS; ++g) _g += ((row) >= cum[g]) ? 1 : 0; dst = _g; }

    const int npairs = (n_rows + 1) >> 1;

    for (int p = wid; p < npairs; p += nwaves) {
        const int row0 = p * 2;
        const int row1 = row0 + 1;
        int gid0, gid1;
        GID_OF(row0, gid0);
        const bool have1 = (row1 < n_rows);
        if (have1) { GID_OF(row1, gid1); } else { gid1 = gid0; }

        if (have1 && gid0 == gid1) {
            // ---- paired fast path: shared w/bias chunk loads ----
            const float a0 = ascale[row0], a1 = ascale[row1];
            const float q_s = qscale[gid0];
            const int* xr0 = x + (long)row0 * TWO_H;
            const int* xr1 = x + (long)row1 * TWO_H;
            const float* wrow = wscale + (long)gid0 * TWO_H;

            vh2 oa[16], ob[16];
            float lmax0 = 0.0f, lmax1 = 0.0f;

#pragma unroll
            for (int c = 0; c < 8; ++c) {
                const int cg = c * 256 + lane * 4;

                vf4 wg = *(const vf4*)(wrow + cg);
                vf4 wu = *(const vf4*)(wrow + HALF_H + cg);
                vf4 bg = *(const vf4*)(bias + cg);
                vf4 bu = *(const vf4*)(bias + HALF_H + cg);
                vi4 g0 = *(const vi4*)(xr0 + cg);
                vi4 u0 = *(const vi4*)(xr0 + HALF_H + cg);
                vi4 g1 = *(const vi4*)(xr1 + cg);
                vi4 u1 = *(const vi4*)(xr1 + HALF_H + cg);

                vf4 bwg = bg * wg;   // bias folded: (x+b)*w = x*w + b*w
                vf4 bwu = bu * wu;

                float wgx[4] = {wg.x, wg.y, wg.z, wg.w};
                float wux[4] = {wu.x, wu.y, wu.z, wu.w};
                float bwgx[4] = {bwg.x, bwg.y, bwg.z, bwg.w};
                float bwux[4] = {bwu.x, bwu.y, bwu.z, bwu.w};
                float gi0[4] = {(float)g0.x, (float)g0.y, (float)g0.z, (float)g0.w};
                float ui0[4] = {(float)u0.x, (float)u0.y, (float)u0.z, (float)u0.w};
                float gi1[4] = {(float)g1.x, (float)g1.y, (float)g1.z, (float)g1.w};
                float ui1[4] = {(float)u1.x, (float)u1.y, (float)u1.z, (float)u1.w};

                float o0[4], o1[4];
#pragma unroll
                for (int i = 0; i < 4; ++i) {
                    float gv0 = fmaf(gi0[i], wgx[i], bwgx[i]) * a0;
                    float uv0 = fmaf(ui0[i], wux[i], bwux[i]) * a0;
                    float e0  = __expf(-uv0);
                    float s0  = uv0 * __builtin_amdgcn_rcpf(1.0f + e0);
                    float v0  = s0 * gv0 * q_s;
                    o0[i] = v0;
                    lmax0 = fmaxf(lmax0, fabsf(v0));

                    float gv1 = fmaf(gi1[i], wgx[i], bwgx[i]) * a1;
                    float uv1 = fmaf(ui1[i], wux[i], bwux[i]) * a1;
                    float e1  = __expf(-uv1);
                    float s1  = uv1 * __builtin_amdgcn_rcpf(1.0f + e1);
                    float v1  = s1 * gv1 * q_s;
                    o1[i] = v1;
                    lmax1 = fmaxf(lmax1, fabsf(v1));
                }
                oa[c * 2]     = __builtin_amdgcn_cvt_pkrtz(o0[0], o0[1]);
                oa[c * 2 + 1] = __builtin_amdgcn_cvt_pkrtz(o0[2], o0[3]);
                ob[c * 2]     = __builtin_amdgcn_cvt_pkrtz(o1[0], o1[1]);
                ob[c * 2 + 1] = __builtin_amdgcn_cvt_pkrtz(o1[2], o1[3]);
            }

#pragma unroll
            for (int m = 1; m < 64; m <<= 1) {
                lmax0 = fmaxf(lmax0, __shfl_xor(lmax0, m, 64));
                lmax1 = fmaxf(lmax1, __shfl_xor(lmax1, m, 64));
            }
            const float sc0 = 127.0f / lmax0;
            const float sc1 = 127.0f / lmax1;

            int* or0 = out + (long)row0 * HALF_H;
            int* or1 = out + (long)row1 * HALF_H;
#pragma unroll
            for (int c = 0; c < 8; ++c) {
                const int co = c * 256 + lane * 4;
                float v0[4] = {(float)oa[c*2].x, (float)oa[c*2].y,
                               (float)oa[c*2+1].x, (float)oa[c*2+1].y};
                float v1[4] = {(float)ob[c*2].x, (float)ob[c*2].y,
                               (float)ob[c*2+1].x, (float)ob[c*2+1].y};
                int w0[4], w1[4];
#pragma unroll
                for (int i = 0; i < 4; ++i) {
                    float a = fminf(fmaxf(v0[i] * sc0, -128.0f), 127.0f);
                    float b = fminf(fmaxf(v1[i] * sc1, -128.0f), 127.0f);
                    w0[i] = (int)rintf(a);
                    w1[i] = (int)rintf(b);
                }
                vi4 s0 = {w0[0], w0[1], w0[2], w0[3]};
                vi4 s1 = {w1[0], w1[1], w1[2], w1[3]};
                *(vi4*)(or0 + co) = s0;
                *(vi4*)(or1 + co) = s1;
            }
        } else {
            // ---- fallback: per-row (boundary straddle or odd tail) ----
            const int rcnt = have1 ? 2 : 1;
            for (int r = 0; r < rcnt; ++r) {
                const int row = row0 + r;
                int gid; GID_OF(row, gid);
                const float a_s = ascale[row];
                const float q_s = qscale[gid];
                const int*   xrow = x + (long)row * TWO_H;
                const float* wrow = wscale + (long)gid * TWO_H;

                vh2 o16[16];
                float lmax = 0.0f;
#pragma unroll
                for (int c = 0; c < 8; ++c) {
                    const int cg = c * 256 + lane * 4;
                    vi4 g = *(const vi4*)(xrow + cg);
                    vi4 u = *(const vi4*)(xrow + HALF_H + cg);
                    vf4 wg = *(const vf4*)(wrow + cg);
                    vf4 wu = *(const vf4*)(wrow + HALF_H + cg);
                    vf4 bg = *(const vf4*)(bias + cg);
                    vf4 bu = *(const vf4*)(bias + HALF_H + cg);
                    float gi[4] = {(float)g.x, (float)g.y, (float)g.z, (float)g.w};
                    float ui[4] = {(float)u.x, (float)u.y, (float)u.z, (float)u.w};
                    float wgx[4] = {wg.x, wg.y, wg.z, wg.w};
                    float wux[4] = {wu.x, wu.y, wu.z, wu.w};
                    float bgx[4] = {bg.x, bg.y, bg.z, bg.w};
                    float bux[4] = {bu.x, bu.y, bu.z, bu.w};
                    float ov[4];
#pragma unroll
                    for (int i = 0; i < 4; ++i) {
                        float gv = (gi[i] + bgx[i]) * wgx[i] * a_s;
                        float uv = (ui[i] + bux[i]) * wux[i] * a_s;
                        float e  = __expf(-uv);
                        float sv = uv * __builtin_amdgcn_rcpf(1.0f + e);
                        float o  = sv * gv * q_s;
                        ov[i] = o;
                        lmax = fmaxf(lmax, fabsf(o));
                    }
                    o16[c * 2]     = __builtin_amdgcn_cvt_pkrtz(ov[0], ov[1]);
                    o16[c * 2 + 1] = __builtin_amdgcn_cvt_pkrtz(ov[2], ov[3]);
                }
#pragma unroll
                for (int m = 1; m < 64; m <<= 1)
                    lmax = fmaxf(lmax, __shfl_xor(lmax, m, 64));
                const float scale = 127.0f / lmax;
                int* orow = out + (long)row * HALF_H;
#pragma unroll
                for (int c = 0; c < 8; ++c) {
                    const int co = c * 256 + lane * 4;
                    float ov[4] = {(float)o16[c*2].x, (float)o16[c*2].y,
                                   (float)o16[c*2+1].x, (float)o16[c*2+1].y};
                    int w[4];
#pragma unroll
                    for (int i = 0; i < 4; ++i) {
                        float v = fminf(fmaxf(ov[i] * scale, -128.0f), 127.0f);
                        w[i] = (int)rintf(v);
                    }
                    vi4 wv = {w[0], w[1], w[2], w[3]};
                    *(vi4*)(orow + co) = wv;
                }
            }
        }
    }
#undef GID_OF
}

extern "C" void kernel_launch(void* const* d_in, const int* in_sizes, int n_in,
                              void* d_out, int out_size, void* d_ws, size_t ws_size,
                              hipStream_t stream) {
    const int*   x      = (const int*)d_in[0];
    const float* wscale = (const float*)d_in[1];
    const float* ascale = (const float*)d_in[2];
    const float* bias   = (const float*)d_in[3];
    const float* qscale = (const float*)d_in[4];
    const int*   gindex = (const int*)d_in[5];
    int* out = (int*)d_out;

    const int n_rows = in_sizes[0] / TWO_H;  // 32768

    swiglu_requant_kernel<<<GRID, BLOCK, 0, stream>>>(
        x, wscale, ascale, bias, qscale, gindex, out, n_rows);
}